// Round 16
// baseline (118.288 us; speedup 1.0000x reference)
//
#include <hip/hip_runtime.h>
#include <hip/hip_bf16.h>
#include <stdint.h>

#define E_ 8
#define H_ 1024
#define I_ 2816
#define T_ 512

typedef __attribute__((ext_vector_type(4))) float f32x4;
typedef __attribute__((ext_vector_type(8))) short short8;

typedef __attribute__((address_space(1))) const unsigned GAS;
typedef __attribute__((address_space(3))) unsigned LAS;

__device__ __forceinline__ void dma16(const void* g, void* l) {
    __builtin_amdgcn_global_load_lds((GAS*)g, (LAS*)l, 16, 0, 0);
}
__device__ __forceinline__ unsigned short f2bf(float f) {   // RNE
    return __builtin_bit_cast(unsigned short, __float2bfloat16(f));
}
__device__ __forceinline__ uint32_t pack_rne(float lo, float hi) {
    return (uint32_t)f2bf(lo) | ((uint32_t)f2bf(hi) << 16);
}
// weights hold exact e4m3 values -> bf16 truncation is exact
__device__ __forceinline__ uint32_t pack_trunc(float lo, float hi) {
    return (__builtin_bit_cast(uint32_t, hi) & 0xFFFF0000u) |
           (__builtin_bit_cast(uint32_t, lo) >> 16);
}

#define SB()  __builtin_amdgcn_sched_barrier(0)
#define VM6() asm volatile("s_waitcnt vmcnt(6)" ::: "memory")
#define VM4() asm volatile("s_waitcnt vmcnt(4)" ::: "memory")
#define VM0() asm volatile("s_waitcnt vmcnt(0)" ::: "memory")

// ---- routing + x->bf16 conversion (fused) ----
__global__ __launch_bounds__(256) void route_cvt(const float* __restrict__ x,
                                                 const int* __restrict__ idx,
                                                 int* __restrict__ counts,
                                                 int* __restrict__ bucket,
                                                 unsigned short* __restrict__ xg) {
    int tid = threadIdx.x;
    if (blockIdx.x == 0) {
        if (tid < E_) counts[tid] = 0;
        for (int i = tid; i < E_ * T_; i += 256) bucket[i] = 0;
        __syncthreads();
#pragma unroll
        for (int k = 0; k < 2; ++k) {
            int t = tid + k * 256;
            int e = idx[t];
            int pos = atomicAdd(counts + e, 1);
            bucket[e * T_ + pos] = t;
        }
    }
    int unit = blockIdx.x * 256 + tid;
    const float* xp = x + (size_t)unit * 8;
    float4 a = *(const float4*)xp, b = *(const float4*)(xp + 4);
    uint4 o = make_uint4(pack_rne(a.x, a.y), pack_rne(a.z, a.w),
                         pack_rne(b.x, b.y), pack_rne(b.z, b.w));
    *(uint4*)(xg + (size_t)unit * 8) = o;
}

// ---- GEMM1 v9: 128 tok x 8 f-cols.
// Phase 1 (r13-proven): ALL 16 weight-row DMAs upfront (full-depth HBM
//   stream), consumed with decreasing vmcnt, bf16 B-tile aliases the stage.
// Phase 2: per-wave independent A-pipeline (wave w owns tokens [w*32,w*32+32)):
//   BK=32, depth-4 A-DMA, uniform vmcnt(4), ZERO barriers, B16 LDS-resident.
// LDS: [0,32K) B16 (aliases stage [0,64K)) ; [32K,64K) A 4x8KB ; tok @64K
__global__ __launch_bounds__(256, 2) void gemm1(const unsigned short* __restrict__ xg,
                                                const float* __restrict__ wgu,
                                                const float* __restrict__ sgu_p,
                                                const int* __restrict__ counts,
                                                const int* __restrict__ bucket,
                                                __hip_bfloat16* __restrict__ hbuf) {
    int e = blockIdx.x;
    int f0 = blockIdx.y * 8;
    int cnt = counts[e];

    __shared__ __align__(16) char smem[64 * 1024 + 512];
    int* tok = (int*)(smem + 64 * 1024);
    int tid = threadIdx.x, w = tid >> 6, lane = tid & 63;
    int r16 = lane & 15, kg = lane >> 4;

    // waves 0,1: one bucket read BEFORE the dmas (oldest op retires first,
    // so vmcnt(15-c) still maps exactly to weight chunk c for every wave).
    if (tid < 128) tok[tid] = bucket[e * T_ + tid];
    SB();

    // ---- phase 1: issue ALL 16 row-DMAs (row c = 4KB f32), then convert ----
    const char* gbase = (const char*)wgu + ((size_t)e * 2 * I_ + f0) * H_ * 4;
    const char* ubase = (const char*)wgu + ((size_t)e * 2 * I_ + I_ + f0) * H_ * 4;
    int soff = w * 1024 + lane * 16;

#define P1SRC(c) ((((c) < 8) ? (gbase + (size_t)(c) * 4096) : (ubase + (size_t)((c) - 8) * 4096)) + soff)
#pragma unroll
    for (int c = 0; c < 16; ++c) dma16(P1SRC(c), smem + c * 4096 + soff);
    SB();

    // consume row c: read own f32 bytes -> barrier -> write swizzled bf16.
    // In-place safety (r13-proven): bf16 row c lands in f32 chunk floor(c/2)
    // <= c; the barrier keeps waves lockstep.
#define P1(c, n)                                                              \
    do {                                                                      \
        asm volatile("s_waitcnt vmcnt(" #n ")" ::: "memory"); SB();           \
        float4 v = *(const float4*)(smem + (c) * 4096 + tid * 16);            \
        SB();                                                                 \
        __builtin_amdgcn_s_barrier();                                         \
        uint2 o; o.x = pack_trunc(v.x, v.y); o.y = pack_trunc(v.z, v.w);      \
        *(uint2*)(smem + (c) * 2048 + (((tid >> 1) ^ ((c) & 7)) * 16) + (tid & 1) * 8) = o; \
    } while (0)

    P1(0, 15);  P1(1, 14);  P1(2, 13);  P1(3, 12);
    P1(4, 11);  P1(5, 10);  P1(6, 9);   P1(7, 8);
    P1(8, 7);   P1(9, 6);   P1(10, 5);  P1(11, 4);
    P1(12, 3);  P1(13, 2);  P1(14, 1);  P1(15, 0);
#undef P1
#undef P1SRC
    __syncthreads();                            // B16 visible; vmcnt drained

    // ---- phase 2: 32 K-steps (BK=32). Wave w's A = its own 32 token rows,
    //      64B/row/step, 2 dma/wave/step, depth-4, vmcnt(4), NO barriers. ----
    const char* xb = (const char*)xg;
    const char* srcA[2]; char* dstA[2];
#pragma unroll
    for (int i = 0; i < 2; ++i) {
        int U = (w * 2 + i) * 64 + lane;
        int row = U >> 2, sl = U & 3;           // row in [w*32, w*32+32)
        srcA[i] = xb + (size_t)tok[row] * 2048 + ((sl ^ (row & 3)) * 16);
        dstA[i] = smem + 32 * 1024 + (w * 2 + i) * 1024;
    }
#pragma unroll
    for (int b = 0; b < 3; ++b)
#pragma unroll
        for (int i = 0; i < 2; ++i)
            dma16(srcA[i] + (size_t)b * 64, dstA[i] + b * 8192);

    f32x4 acc[2];
    acc[0] = (f32x4){0, 0, 0, 0};
    acc[1] = (f32x4){0, 0, 0, 0};

    for (int t = 0; t < 32; ++t) {
        VM4();                                   // own step-t dmas landed
        SB();
        const char* Ab = smem + 32 * 1024 + (t & 3) * 8192;
        short8 Bf = *(const short8*)(smem + r16 * 2048 +
                     (((t * 4 + kg) ^ (r16 & 7)) * 16));
#pragma unroll
        for (int m = 0; m < 2; ++m) {
            int tr = w * 32 + m * 16 + r16;
            short8 Af = *(const short8*)(Ab + tr * 64 + ((kg ^ (tr & 3)) * 16));
            acc[m] = __builtin_amdgcn_mfma_f32_16x16x32_bf16(Af, Bf, acc[m], 0, 0, 0);
        }
        int tp = (t + 3 < 32) ? t + 3 : 31;      // strays land in dead buffers
#pragma unroll
        for (int i = 0; i < 2; ++i)
            dma16(srcA[i] + (size_t)tp * 64, dstA[i] + ((t + 3) & 3) * 8192);
    }

    // epilogue: cols 0-7 = gate(f0+r16), 8-15 = up; pair via shfl_xor(8)
    float sgu = sgu_p[0];
#pragma unroll
    for (int m = 0; m < 2; ++m)
#pragma unroll
        for (int j = 0; j < 4; ++j) {
            float self = acc[m][j] * sgu;
            float other = __shfl_xor(self, 8);
            if (r16 < 8) {
                float g = self, u = other;
                float hv = (g / (1.f + __expf(-g))) * u;
                int tk = w * 32 + m * 16 + kg * 4 + j;
                if (tk < cnt)
                    hbuf[(size_t)tok[tk] * I_ + f0 + r16] = __float2bfloat16(hv);
            }
        }
}

// ---- GEMM2 (r7 verbatim): 64 tok x 16 hcols, BK=128, 22 steps, depth-3 DMA ----
// LDS: A bf16 3x16KB @0 ; B f32 3x8KB @48KB ; tok @72KB
__global__ __launch_bounds__(256) void gemm2(const __hip_bfloat16* __restrict__ hbuf,
                                             const float* __restrict__ wd,
                                             const float* __restrict__ sd_p,
                                             const int* __restrict__ counts,
                                             const int* __restrict__ bucket,
                                             float* __restrict__ out) {
    int e = blockIdx.x >> 1, mt = blockIdx.x & 1;
    int cnt = counts[e];
    if (mt * 64 >= cnt) return;
    int h0 = blockIdx.y * 16;

    __shared__ __align__(16) char smem[72 * 1024 + 256];
    int* tok = (int*)(smem + 72 * 1024);
    int tid = threadIdx.x, w = tid >> 6, lane = tid & 63;
    int r16 = lane & 15, kg = lane >> 4;

    float sd = sd_p[0];
    asm volatile("" :: "v"(sd));

    if (tid < 64) tok[tid] = bucket[e * T_ + mt * 64 + tid];
    __syncthreads();

    const char* hb = (const char*)hbuf;
    const char* srcA[4]; char* dstA[4];
#pragma unroll
    for (int i = 0; i < 4; ++i) {
        int U = (w * 4 + i) * 64 + lane;
        int row = U >> 4, sl = U & 15;
        srcA[i] = hb + (size_t)tok[row] * (I_ * 2) + (size_t)((sl ^ (row & 15)) * 16);
        dstA[i] = smem + (w * 4 + i) * 1024;
    }
    const char* wd_e = (const char*)(wd + (size_t)e * (size_t)H_ * I_);
    const char* srcB[2]; char* dstB[2];
#pragma unroll
    for (int i = 0; i < 2; ++i) {
        int U = (w * 2 + i) * 64 + lane;
        int row = U >> 5, sl = U & 31;
        srcB[i] = wd_e + (size_t)(h0 + row) * ((size_t)I_ * 4) + (size_t)((sl ^ (row & 15)) * 16);
        dstB[i] = smem + 48 * 1024 + (w * 2 + i) * 1024;
    }

#define G2_ISSUE(s, buf)                                                     \
    do {                                                                     \
        _Pragma("unroll")                                                    \
        for (int i = 0; i < 4; ++i) dma16(srcA[i] + (size_t)(s) * 256, dstA[i] + (buf) * 16384); \
        _Pragma("unroll")                                                    \
        for (int i = 0; i < 2; ++i) dma16(srcB[i] + (size_t)(s) * 512, dstB[i] + (buf) * 8192);  \
    } while (0)

    G2_ISSUE(0, 0);
    G2_ISSUE(1, 1);

    f32x4 acc = (f32x4){0, 0, 0, 0};

    for (int t = 0; t < 22; ++t) {
        VM6();
        __builtin_amdgcn_s_barrier();
        int tp = (t + 2 < 22) ? t + 2 : 21;
        G2_ISSUE(tp, (t + 2) % 3);
        const char* Ab = smem + (t % 3) * 16384;
        const char* Bb = smem + 48 * 1024 + (t % 3) * 8192;
#pragma unroll
        for (int kk = 0; kk < 4; ++kk) {
            int bo = r16 * 512 + kk * 128 + kg * 32;
            int sw = r16 << 4;
            float4 b0 = *(float4*)(Bb + (bo ^ sw));
            float4 b1 = *(float4*)(Bb + ((bo + 16) ^ sw));
            uint4 bu = make_uint4(pack_trunc(b0.x, b0.y), pack_trunc(b0.z, b0.w),
                                  pack_trunc(b1.x, b1.y), pack_trunc(b1.z, b1.w));
            short8 B = __builtin_bit_cast(short8, bu);
            int ar = w * 16 + r16;
            short8 A = *(short8*)(Ab + ((ar * 256 + kk * 64 + kg * 16) ^ ((ar & 15) << 4)));
            acc = __builtin_amdgcn_mfma_f32_16x16x32_bf16(A, B, acc, 0, 0, 0);
        }
    }
    VM0();

#pragma unroll
    for (int j = 0; j < 4; ++j) {
        int tr = w * 16 + kg * 4 + j;
        int pos = mt * 64 + tr;
        if (pos < cnt)
            out[(size_t)tok[tr] * H_ + h0 + r16] = acc[j] * sd;
    }
#undef G2_ISSUE
}

extern "C" void kernel_launch(void* const* d_in, const int* in_sizes, int n_in,
                              void* d_out, int out_size, void* d_ws, size_t ws_size,
                              hipStream_t stream) {
    const float* x    = (const float*)d_in[0];
    const int*   eidx = (const int*)d_in[1];
    const float* wgu  = (const float*)d_in[2];   // fp8 values stored as f32
    const float* sgu  = (const float*)d_in[3];
    const float* wd   = (const float*)d_in[4];   // fp8 values stored as f32
    const float* sd   = (const float*)d_in[5];
    float* out = (float*)d_out;

    char* ws = (char*)d_ws;
    int* counts = (int*)ws;                                   // 32 B
    int* bucket = (int*)(ws + 1024);                          // 16 KB
    unsigned short* xg = (unsigned short*)(ws + 32768);       // 1 MB bf16 x
    __hip_bfloat16* hbuf = (__hip_bfloat16*)(ws + 1114112);   // 2.88 MB

    route_cvt<<<256, 256, 0, stream>>>(x, eidx, counts, bucket, xg);
    gemm1<<<dim3(E_, I_ / 8), 256, 0, stream>>>(xg, wgu, sgu, counts, bucket, hbuf);
    gemm2<<<dim3(E_ * 2, H_ / 16), 256, 0, stream>>>(hbuf, wd, sd, counts, bucket, out);
}

// Round 17
// 115.909 us; speedup vs baseline: 1.0205x; 1.0205x over previous
//
#include <hip/hip_runtime.h>
#include <hip/hip_bf16.h>
#include <stdint.h>

#define E_ 8
#define H_ 1024
#define I_ 2816
#define T_ 512

typedef __attribute__((ext_vector_type(4))) float f32x4;
typedef __attribute__((ext_vector_type(8))) short short8;

typedef __attribute__((address_space(1))) const unsigned GAS;
typedef __attribute__((address_space(3))) unsigned LAS;

__device__ __forceinline__ void dma16(const void* g, void* l) {
    __builtin_amdgcn_global_load_lds((GAS*)g, (LAS*)l, 16, 0, 0);
}
__device__ __forceinline__ unsigned short f2bf(float f) {   // RNE
    return __builtin_bit_cast(unsigned short, __float2bfloat16(f));
}
__device__ __forceinline__ uint32_t pack_rne(float lo, float hi) {
    return (uint32_t)f2bf(lo) | ((uint32_t)f2bf(hi) << 16);
}
// weights hold exact e4m3 values -> bf16 truncation is exact
__device__ __forceinline__ uint32_t pack_trunc(float lo, float hi) {
    return (__builtin_bit_cast(uint32_t, hi) & 0xFFFF0000u) |
           (__builtin_bit_cast(uint32_t, lo) >> 16);
}

#define VM6() asm volatile("s_waitcnt vmcnt(6)" ::: "memory")
#define VM0() asm volatile("s_waitcnt vmcnt(0)" ::: "memory")

// ---- routing + x->bf16 conversion (fused) ----
__global__ __launch_bounds__(256) void route_cvt(const float* __restrict__ x,
                                                 const int* __restrict__ idx,
                                                 int* __restrict__ counts,
                                                 int* __restrict__ bucket,
                                                 unsigned short* __restrict__ xg) {
    int tid = threadIdx.x;
    if (blockIdx.x == 0) {
        if (tid < E_) counts[tid] = 0;
        for (int i = tid; i < E_ * T_; i += 256) bucket[i] = 0;
        __syncthreads();
#pragma unroll
        for (int k = 0; k < 2; ++k) {
            int t = tid + k * 256;
            int e = idx[t];
            int pos = atomicAdd(counts + e, 1);
            bucket[e * T_ + pos] = t;
        }
    }
    int unit = blockIdx.x * 256 + tid;
    const float* xp = x + (size_t)unit * 8;
    float4 a = *(const float4*)xp, b = *(const float4*)(xp + 4);
    uint4 o = make_uint4(pack_rne(a.x, a.y), pack_rne(a.z, a.w),
                         pack_rne(b.x, b.y), pack_rne(b.z, b.w));
    *(uint4*)(xg + (size_t)unit * 8) = o;
}

// ---- GEMM1 v10 (gemm2 template, byte-minimized): 64 tok x 32 f-cols
//      (64 weight rows = 32 gate + 32 up), BK=64, 16 steps, depth-3 VM6 DMA.
//      grid (88, 16): f-block fast => expert spread over all XCDs.
// LDS: A bf16 3x8KB @0 ; B f32 3x16KB @24KB ; tok @72KB => 72.5KB, 2 blk/CU
__global__ __launch_bounds__(256) void gemm1(const unsigned short* __restrict__ xg,
                                             const float* __restrict__ wgu,
                                             const float* __restrict__ sgu_p,
                                             const int* __restrict__ counts,
                                             const int* __restrict__ bucket,
                                             __hip_bfloat16* __restrict__ hbuf) {
    int e = blockIdx.y >> 1, mt = blockIdx.y & 1;
    int cnt = counts[e];
    if (mt * 64 >= cnt) return;
    int f0 = blockIdx.x * 32;

    __shared__ __align__(16) char smem[72 * 1024 + 256];
    int* tok = (int*)(smem + 72 * 1024);
    int tid = threadIdx.x, w = tid >> 6, lane = tid & 63;
    int r16 = lane & 15, kg = lane >> 4;

    float sgu = sgu_p[0];
    asm volatile("" :: "v"(sgu));

    if (tid < 64) tok[tid] = bucket[e * T_ + mt * 64 + tid];
    __syncthreads();

    // A: xg bf16, 64 rows x 128B/step (8 slots of 16B), 2 dma/wave
    const char* xb = (const char*)xg;
    const char* srcA[2]; char* dstA[2];
#pragma unroll
    for (int i = 0; i < 2; ++i) {
        int U = (w * 2 + i) * 64 + lane;
        int row = U >> 3, sl = U & 7;
        srcA[i] = xb + (size_t)tok[row] * 2048 + ((sl ^ (row & 7)) * 16);
        dstA[i] = smem + (w * 2 + i) * 1024;
    }
    // B: w_gu f32, 64 rows (32 gate @f0, 32 up @I_+f0) x 256B/step (16 slots)
    const char* wbase = (const char*)wgu + (size_t)e * 2 * (size_t)I_ * H_ * 4;
    const char* srcB[4]; char* dstB[4];
#pragma unroll
    for (int i = 0; i < 4; ++i) {
        int U = (w * 4 + i) * 64 + lane;
        int row = U >> 4, sl = U & 15;
        int wr = (row < 32) ? (f0 + row) : (I_ + f0 + row - 32);
        srcB[i] = wbase + (size_t)wr * 4096 + ((sl ^ (row & 15)) * 16);
        dstB[i] = smem + 24 * 1024 + (w * 4 + i) * 1024;
    }

#define G1_ISSUE(s, buf)                                                     \
    do {                                                                     \
        _Pragma("unroll")                                                    \
        for (int i = 0; i < 2; ++i) dma16(srcA[i] + (size_t)(s) * 128, dstA[i] + (buf) * 8192);  \
        _Pragma("unroll")                                                    \
        for (int i = 0; i < 4; ++i) dma16(srcB[i] + (size_t)(s) * 256, dstB[i] + (buf) * 16384); \
    } while (0)

    G1_ISSUE(0, 0);
    G1_ISSUE(1, 1);

    f32x4 acc[4];
#pragma unroll
    for (int n = 0; n < 4; ++n) acc[n] = (f32x4){0, 0, 0, 0};

    for (int t = 0; t < 16; ++t) {
        VM6();
        __builtin_amdgcn_s_barrier();
        int tp = (t + 2 < 16) ? t + 2 : 15;
        G1_ISSUE(tp, (t + 2) % 3);
        const char* Ab = smem + (t % 3) * 8192;
        const char* Bb = smem + 24 * 1024 + (t % 3) * 16384;
#pragma unroll
        for (int kk = 0; kk < 2; ++kk) {
            int arow = w * 16 + r16;
            short8 Af = *(const short8*)(Ab + arow * 128 + (((kk * 4 + kg) ^ (arow & 7)) * 16));
#pragma unroll
            for (int n = 0; n < 4; ++n) {
                int brow = n * 16 + r16;
                int slot = kk * 8 + kg * 2;
                float4 b0 = *(const float4*)(Bb + brow * 256 + ((slot ^ (brow & 15)) * 16));
                float4 b1 = *(const float4*)(Bb + brow * 256 + (((slot + 1) ^ (brow & 15)) * 16));
                uint4 bu = make_uint4(pack_trunc(b0.x, b0.y), pack_trunc(b0.z, b0.w),
                                      pack_trunc(b1.x, b1.y), pack_trunc(b1.z, b1.w));
                short8 Bf = __builtin_bit_cast(short8, bu);
                acc[n] = __builtin_amdgcn_mfma_f32_16x16x32_bf16(Af, Bf, acc[n], 0, 0, 0);
            }
        }
    }
    VM0();

    // epilogue: acc[0,1] = gate cols f0+n*16+r16 ; acc[2,3] = up, same cols.
#pragma unroll
    for (int n = 0; n < 2; ++n)
#pragma unroll
        for (int j = 0; j < 4; ++j) {
            int tr = w * 16 + kg * 4 + j;
            int pos = mt * 64 + tr;
            if (pos < cnt) {
                float g = acc[n][j] * sgu;
                float u = acc[n + 2][j] * sgu;
                float hv = (g / (1.f + __expf(-g))) * u;
                hbuf[(size_t)tok[tr] * I_ + f0 + n * 16 + r16] = __float2bfloat16(hv);
            }
        }
#undef G1_ISSUE
}

// ---- GEMM2 (r7 structure; grid axes swapped): 64 tok x 16 hcols, BK=128 ----
// LDS: A bf16 3x16KB @0 ; B f32 3x8KB @48KB ; tok @72KB
__global__ __launch_bounds__(256) void gemm2(const __hip_bfloat16* __restrict__ hbuf,
                                             const float* __restrict__ wd,
                                             const float* __restrict__ sd_p,
                                             const int* __restrict__ counts,
                                             const int* __restrict__ bucket,
                                             float* __restrict__ out) {
    int e = blockIdx.y >> 1, mt = blockIdx.y & 1;
    int cnt = counts[e];
    if (mt * 64 >= cnt) return;
    int h0 = blockIdx.x * 16;

    __shared__ __align__(16) char smem[72 * 1024 + 256];
    int* tok = (int*)(smem + 72 * 1024);
    int tid = threadIdx.x, w = tid >> 6, lane = tid & 63;
    int r16 = lane & 15, kg = lane >> 4;

    float sd = sd_p[0];
    asm volatile("" :: "v"(sd));

    if (tid < 64) tok[tid] = bucket[e * T_ + mt * 64 + tid];
    __syncthreads();

    const char* hb = (const char*)hbuf;
    const char* srcA[4]; char* dstA[4];
#pragma unroll
    for (int i = 0; i < 4; ++i) {
        int U = (w * 4 + i) * 64 + lane;
        int row = U >> 4, sl = U & 15;
        srcA[i] = hb + (size_t)tok[row] * (I_ * 2) + (size_t)((sl ^ (row & 15)) * 16);
        dstA[i] = smem + (w * 4 + i) * 1024;
    }
    const char* wd_e = (const char*)(wd + (size_t)e * (size_t)H_ * I_);
    const char* srcB[2]; char* dstB[2];
#pragma unroll
    for (int i = 0; i < 2; ++i) {
        int U = (w * 2 + i) * 64 + lane;
        int row = U >> 5, sl = U & 31;
        srcB[i] = wd_e + (size_t)(h0 + row) * ((size_t)I_ * 4) + (size_t)((sl ^ (row & 15)) * 16);
        dstB[i] = smem + 48 * 1024 + (w * 2 + i) * 1024;
    }

#define G2_ISSUE(s, buf)                                                     \
    do {                                                                     \
        _Pragma("unroll")                                                    \
        for (int i = 0; i < 4; ++i) dma16(srcA[i] + (size_t)(s) * 256, dstA[i] + (buf) * 16384); \
        _Pragma("unroll")                                                    \
        for (int i = 0; i < 2; ++i) dma16(srcB[i] + (size_t)(s) * 512, dstB[i] + (buf) * 8192);  \
    } while (0)

    G2_ISSUE(0, 0);
    G2_ISSUE(1, 1);

    f32x4 acc = (f32x4){0, 0, 0, 0};

    for (int t = 0; t < 22; ++t) {
        VM6();
        __builtin_amdgcn_s_barrier();
        int tp = (t + 2 < 22) ? t + 2 : 21;
        G2_ISSUE(tp, (t + 2) % 3);
        const char* Ab = smem + (t % 3) * 16384;
        const char* Bb = smem + 48 * 1024 + (t % 3) * 8192;
#pragma unroll
        for (int kk = 0; kk < 4; ++kk) {
            int bo = r16 * 512 + kk * 128 + kg * 32;
            int sw = r16 << 4;
            float4 b0 = *(float4*)(Bb + (bo ^ sw));
            float4 b1 = *(float4*)(Bb + ((bo + 16) ^ sw));
            uint4 bu = make_uint4(pack_trunc(b0.x, b0.y), pack_trunc(b0.z, b0.w),
                                  pack_trunc(b1.x, b1.y), pack_trunc(b1.z, b1.w));
            short8 B = __builtin_bit_cast(short8, bu);
            int ar = w * 16 + r16;
            short8 A = *(short8*)(Ab + ((ar * 256 + kk * 64 + kg * 16) ^ ((ar & 15) << 4)));
            acc = __builtin_amdgcn_mfma_f32_16x16x32_bf16(A, B, acc, 0, 0, 0);
        }
    }
    VM0();

#pragma unroll
    for (int j = 0; j < 4; ++j) {
        int tr = w * 16 + kg * 4 + j;
        int pos = mt * 64 + tr;
        if (pos < cnt)
            out[(size_t)tok[tr] * H_ + h0 + r16] = acc[j] * sd;
    }
#undef G2_ISSUE
}

extern "C" void kernel_launch(void* const* d_in, const int* in_sizes, int n_in,
                              void* d_out, int out_size, void* d_ws, size_t ws_size,
                              hipStream_t stream) {
    const float* x    = (const float*)d_in[0];
    const int*   eidx = (const int*)d_in[1];
    const float* wgu  = (const float*)d_in[2];   // fp8 values stored as f32
    const float* sgu  = (const float*)d_in[3];
    const float* wd   = (const float*)d_in[4];   // fp8 values stored as f32
    const float* sd   = (const float*)d_in[5];
    float* out = (float*)d_out;

    char* ws = (char*)d_ws;
    int* counts = (int*)ws;                                   // 32 B
    int* bucket = (int*)(ws + 1024);                          // 16 KB
    unsigned short* xg = (unsigned short*)(ws + 32768);       // 1 MB bf16 x
    __hip_bfloat16* hbuf = (__hip_bfloat16*)(ws + 1114112);   // 2.88 MB

    route_cvt<<<256, 256, 0, stream>>>(x, eidx, counts, bucket, xg);
    gemm1<<<dim3(I_ / 32, E_ * 2), 256, 0, stream>>>(xg, wgu, sgu, counts, bucket, hbuf);
    gemm2<<<dim3(H_ / 16, E_ * 2), 256, 0, stream>>>(hbuf, wd, sd, counts, bucket, out);
}

// Round 18
// 114.853 us; speedup vs baseline: 1.0299x; 1.0092x over previous
//
#include <hip/hip_runtime.h>
#include <hip/hip_bf16.h>
#include <stdint.h>

#define E_ 8
#define H_ 1024
#define I_ 2816
#define T_ 512
#define XROW 2112   // padded xg row stride in bytes (2048 data + 64 pad, non-pow2)

typedef __attribute__((ext_vector_type(4))) float f32x4;
typedef __attribute__((ext_vector_type(8))) short short8;

typedef __attribute__((address_space(1))) const unsigned GAS;
typedef __attribute__((address_space(3))) unsigned LAS;

__device__ __forceinline__ void dma16(const void* g, void* l) {
    __builtin_amdgcn_global_load_lds((GAS*)g, (LAS*)l, 16, 0, 0);
}
__device__ __forceinline__ unsigned short f2bf(float f) {   // RNE
    return __builtin_bit_cast(unsigned short, __float2bfloat16(f));
}
__device__ __forceinline__ uint32_t pack_rne(float lo, float hi) {
    return (uint32_t)f2bf(lo) | ((uint32_t)f2bf(hi) << 16);
}
// weights hold exact e4m3 values -> bf16 truncation is exact
__device__ __forceinline__ uint32_t pack_trunc(float lo, float hi) {
    return (__builtin_bit_cast(uint32_t, hi) & 0xFFFF0000u) |
           (__builtin_bit_cast(uint32_t, lo) >> 16);
}

#define SB()  __builtin_amdgcn_sched_barrier(0)
#define VM6() asm volatile("s_waitcnt vmcnt(6)" ::: "memory")
#define VM4() asm volatile("s_waitcnt vmcnt(4)" ::: "memory")
#define VM0() asm volatile("s_waitcnt vmcnt(0)" ::: "memory")

// ---- routing + x->bf16 conversion (fused); xg rows padded to XROW ----
__global__ __launch_bounds__(256) void route_cvt(const float* __restrict__ x,
                                                 const int* __restrict__ idx,
                                                 int* __restrict__ counts,
                                                 int* __restrict__ bucket,
                                                 char* __restrict__ xgb) {
    int tid = threadIdx.x;
    if (blockIdx.x == 0) {
        if (tid < E_) counts[tid] = 0;
        for (int i = tid; i < E_ * T_; i += 256) bucket[i] = 0;
        __syncthreads();
#pragma unroll
        for (int k = 0; k < 2; ++k) {
            int t = tid + k * 256;
            int e = idx[t];
            int pos = atomicAdd(counts + e, 1);
            bucket[e * T_ + pos] = t;
        }
    }
    int unit = blockIdx.x * 256 + tid;           // 65536 units of 8 f32 -> 16B bf16
    const float* xp = x + (size_t)unit * 8;
    float4 a = *(const float4*)xp, b = *(const float4*)(xp + 4);
    uint4 o = make_uint4(pack_rne(a.x, a.y), pack_rne(a.z, a.w),
                         pack_rne(b.x, b.y), pack_rne(b.z, b.w));
    *(uint4*)(xgb + (size_t)(unit >> 7) * XROW + (unit & 127) * 16) = o;
}

// ---- GEMM1 v11 (= r16 v9 + padded-xg A stream): 128 tok x 8 f-cols.
// Phase 1: ALL 16 weight-row DMAs upfront (contiguous 64KB, no pow2 aliasing),
//   consumed with decreasing vmcnt, bf16 B-tile aliases the stage in place.
// Phase 2: per-wave independent A-pipeline, BK=32, depth-4, vmcnt(4),
//   ZERO barriers; A rows now at XROW=2112B stride (non-pow2).
// LDS: [0,32K) B16 (aliases stage [0,64K)) ; [32K,64K) A 4x8KB ; tok @64K
__global__ __launch_bounds__(256, 2) void gemm1(const char* __restrict__ xgb,
                                                const float* __restrict__ wgu,
                                                const float* __restrict__ sgu_p,
                                                const int* __restrict__ counts,
                                                const int* __restrict__ bucket,
                                                __hip_bfloat16* __restrict__ hbuf) {
    int e = blockIdx.x;
    int f0 = blockIdx.y * 8;
    int cnt = counts[e];

    __shared__ __align__(16) char smem[64 * 1024 + 512];
    int* tok = (int*)(smem + 64 * 1024);
    int tid = threadIdx.x, w = tid >> 6, lane = tid & 63;
    int r16 = lane & 15, kg = lane >> 4;

    // waves 0,1: one bucket read BEFORE the dmas (oldest op retires first,
    // so vmcnt(15-c) still maps exactly to weight chunk c for every wave).
    if (tid < 128) tok[tid] = bucket[e * T_ + tid];
    SB();

    // ---- phase 1: issue ALL 16 row-DMAs (row c = 4KB f32, contiguous) ----
    const char* gbase = (const char*)wgu + ((size_t)e * 2 * I_ + f0) * H_ * 4;
    const char* ubase = (const char*)wgu + ((size_t)e * 2 * I_ + I_ + f0) * H_ * 4;
    int soff = w * 1024 + lane * 16;

#define P1SRC(c) ((((c) < 8) ? (gbase + (size_t)(c) * 4096) : (ubase + (size_t)((c) - 8) * 4096)) + soff)
#pragma unroll
    for (int c = 0; c < 16; ++c) dma16(P1SRC(c), smem + c * 4096 + soff);
    SB();

    // consume row c: read own f32 bytes -> barrier -> write swizzled bf16.
    // In-place safety (r13-proven): bf16 row c lands in f32 chunk floor(c/2)
    // <= c; the barrier keeps waves lockstep.
#define P1(c, n)                                                              \
    do {                                                                      \
        asm volatile("s_waitcnt vmcnt(" #n ")" ::: "memory"); SB();           \
        float4 v = *(const float4*)(smem + (c) * 4096 + tid * 16);            \
        SB();                                                                 \
        __builtin_amdgcn_s_barrier();                                         \
        uint2 o; o.x = pack_trunc(v.x, v.y); o.y = pack_trunc(v.z, v.w);      \
        *(uint2*)(smem + (c) * 2048 + (((tid >> 1) ^ ((c) & 7)) * 16) + (tid & 1) * 8) = o; \
    } while (0)

    P1(0, 15);  P1(1, 14);  P1(2, 13);  P1(3, 12);
    P1(4, 11);  P1(5, 10);  P1(6, 9);   P1(7, 8);
    P1(8, 7);   P1(9, 6);   P1(10, 5);  P1(11, 4);
    P1(12, 3);  P1(13, 2);  P1(14, 1);  P1(15, 0);
#undef P1
#undef P1SRC
    __syncthreads();                            // B16 visible; vmcnt drained

    // ---- phase 2: 32 K-steps (BK=32). Wave w's A = its own 32 token rows,
    //      64B/row/step, 2 dma/wave/step, depth-4, vmcnt(4), NO barriers. ----
    const char* srcA[2]; char* dstA[2];
#pragma unroll
    for (int i = 0; i < 2; ++i) {
        int U = (w * 2 + i) * 64 + lane;
        int row = U >> 2, sl = U & 3;           // row in [w*32, w*32+32)
        srcA[i] = xgb + (size_t)tok[row] * XROW + ((sl ^ (row & 3)) * 16);
        dstA[i] = smem + 32 * 1024 + (w * 2 + i) * 1024;
    }
#pragma unroll
    for (int b = 0; b < 3; ++b)
#pragma unroll
        for (int i = 0; i < 2; ++i)
            dma16(srcA[i] + (size_t)b * 64, dstA[i] + b * 8192);

    f32x4 acc[2];
    acc[0] = (f32x4){0, 0, 0, 0};
    acc[1] = (f32x4){0, 0, 0, 0};

    for (int t = 0; t < 32; ++t) {
        VM4();                                   // own step-t dmas landed
        SB();
        const char* Ab = smem + 32 * 1024 + (t & 3) * 8192;
        short8 Bf = *(const short8*)(smem + r16 * 2048 +
                     (((t * 4 + kg) ^ (r16 & 7)) * 16));
#pragma unroll
        for (int m = 0; m < 2; ++m) {
            int tr = w * 32 + m * 16 + r16;
            short8 Af = *(const short8*)(Ab + tr * 64 + ((kg ^ (tr & 3)) * 16));
            acc[m] = __builtin_amdgcn_mfma_f32_16x16x32_bf16(Af, Bf, acc[m], 0, 0, 0);
        }
        int tp = (t + 3 < 32) ? t + 3 : 31;      // strays land in dead buffers
#pragma unroll
        for (int i = 0; i < 2; ++i)
            dma16(srcA[i] + (size_t)tp * 64, dstA[i] + ((t + 3) & 3) * 8192);
    }

    // epilogue: cols 0-7 = gate(f0+r16), 8-15 = up; pair via shfl_xor(8)
    float sgu = sgu_p[0];
#pragma unroll
    for (int m = 0; m < 2; ++m)
#pragma unroll
        for (int j = 0; j < 4; ++j) {
            float self = acc[m][j] * sgu;
            float other = __shfl_xor(self, 8);
            if (r16 < 8) {
                float g = self, u = other;
                float hv = (g / (1.f + __expf(-g))) * u;
                int tk = w * 32 + m * 16 + kg * 4 + j;
                if (tk < cnt)
                    hbuf[(size_t)tok[tk] * I_ + f0 + r16] = __float2bfloat16(hv);
            }
        }
}

// ---- GEMM2 (r17 verbatim): 64 tok x 16 hcols, BK=128, 22 steps, depth-3 DMA ----
// LDS: A bf16 3x16KB @0 ; B f32 3x8KB @48KB ; tok @72KB
__global__ __launch_bounds__(256) void gemm2(const __hip_bfloat16* __restrict__ hbuf,
                                             const float* __restrict__ wd,
                                             const float* __restrict__ sd_p,
                                             const int* __restrict__ counts,
                                             const int* __restrict__ bucket,
                                             float* __restrict__ out) {
    int e = blockIdx.y >> 1, mt = blockIdx.y & 1;
    int cnt = counts[e];
    if (mt * 64 >= cnt) return;
    int h0 = blockIdx.x * 16;

    __shared__ __align__(16) char smem[72 * 1024 + 256];
    int* tok = (int*)(smem + 72 * 1024);
    int tid = threadIdx.x, w = tid >> 6, lane = tid & 63;
    int r16 = lane & 15, kg = lane >> 4;

    float sd = sd_p[0];
    asm volatile("" :: "v"(sd));

    if (tid < 64) tok[tid] = bucket[e * T_ + mt * 64 + tid];
    __syncthreads();

    const char* hb = (const char*)hbuf;
    const char* srcA[4]; char* dstA[4];
#pragma unroll
    for (int i = 0; i < 4; ++i) {
        int U = (w * 4 + i) * 64 + lane;
        int row = U >> 4, sl = U & 15;
        srcA[i] = hb + (size_t)tok[row] * (I_ * 2) + (size_t)((sl ^ (row & 15)) * 16);
        dstA[i] = smem + (w * 4 + i) * 1024;
    }
    const char* wd_e = (const char*)(wd + (size_t)e * (size_t)H_ * I_);
    const char* srcB[2]; char* dstB[2];
#pragma unroll
    for (int i = 0; i < 2; ++i) {
        int U = (w * 2 + i) * 64 + lane;
        int row = U >> 5, sl = U & 31;
        srcB[i] = wd_e + (size_t)(h0 + row) * ((size_t)I_ * 4) + (size_t)((sl ^ (row & 15)) * 16);
        dstB[i] = smem + 48 * 1024 + (w * 2 + i) * 1024;
    }

#define G2_ISSUE(s, buf)                                                     \
    do {                                                                     \
        _Pragma("unroll")                                                    \
        for (int i = 0; i < 4; ++i) dma16(srcA[i] + (size_t)(s) * 256, dstA[i] + (buf) * 16384); \
        _Pragma("unroll")                                                    \
        for (int i = 0; i < 2; ++i) dma16(srcB[i] + (size_t)(s) * 512, dstB[i] + (buf) * 8192);  \
    } while (0)

    G2_ISSUE(0, 0);
    G2_ISSUE(1, 1);

    f32x4 acc = (f32x4){0, 0, 0, 0};

    for (int t = 0; t < 22; ++t) {
        VM6();
        __builtin_amdgcn_s_barrier();
        int tp = (t + 2 < 22) ? t + 2 : 21;
        G2_ISSUE(tp, (t + 2) % 3);
        const char* Ab = smem + (t % 3) * 16384;
        const char* Bb = smem + 48 * 1024 + (t % 3) * 8192;
#pragma unroll
        for (int kk = 0; kk < 4; ++kk) {
            int bo = r16 * 512 + kk * 128 + kg * 32;
            int sw = r16 << 4;
            float4 b0 = *(float4*)(Bb + (bo ^ sw));
            float4 b1 = *(float4*)(Bb + ((bo + 16) ^ sw));
            uint4 bu = make_uint4(pack_trunc(b0.x, b0.y), pack_trunc(b0.z, b0.w),
                                  pack_trunc(b1.x, b1.y), pack_trunc(b1.z, b1.w));
            short8 B = __builtin_bit_cast(short8, bu);
            int ar = w * 16 + r16;
            short8 A = *(short8*)(Ab + ((ar * 256 + kk * 64 + kg * 16) ^ ((ar & 15) << 4)));
            acc = __builtin_amdgcn_mfma_f32_16x16x32_bf16(A, B, acc, 0, 0, 0);
        }
    }
    VM0();

#pragma unroll
    for (int j = 0; j < 4; ++j) {
        int tr = w * 16 + kg * 4 + j;
        int pos = mt * 64 + tr;
        if (pos < cnt)
            out[(size_t)tok[tr] * H_ + h0 + r16] = acc[j] * sd;
    }
#undef G2_ISSUE
}

extern "C" void kernel_launch(void* const* d_in, const int* in_sizes, int n_in,
                              void* d_out, int out_size, void* d_ws, size_t ws_size,
                              hipStream_t stream) {
    const float* x    = (const float*)d_in[0];
    const int*   eidx = (const int*)d_in[1];
    const float* wgu  = (const float*)d_in[2];   // fp8 values stored as f32
    const float* sgu  = (const float*)d_in[3];
    const float* wd   = (const float*)d_in[4];   // fp8 values stored as f32
    const float* sd   = (const float*)d_in[5];
    float* out = (float*)d_out;

    char* ws = (char*)d_ws;
    int* counts = (int*)ws;                                   // 32 B
    int* bucket = (int*)(ws + 1024);                          // 16 KB
    char* xgb = ws + 32768;                                   // 512 x 2112 B = 1.03 MB
    __hip_bfloat16* hbuf = (__hip_bfloat16*)(ws + 1114112);   // 2.88 MB

    route_cvt<<<256, 256, 0, stream>>>(x, eidx, counts, bucket, xgb);
    gemm1<<<dim3(E_, I_ / 8), 256, 0, stream>>>(xgb, wgu, sgu, counts, bucket, hbuf);
    gemm2<<<dim3(H_ / 16, E_ * 2), 256, 0, stream>>>(hbuf, wd, sd, counts, bucket, out);
}